// Round 5
// baseline (122.182 us; speedup 1.0000x reference)
//
#include <hip/hip_runtime.h>
#include <stdint.h>

// ---------------------------------------------------------------------------
// FastHelgasonLayer: weights are IFFTs of 16-sparse spectra => exactly rank-32.
//   W_fc = U_fc(2048x32)V_fc(32x8192), W_proj = U_pr(8192x32)V_pr(32x2048)
// Round 5: 3-kernel split for TLP. T1(0.5MB)/T2-partials(2MB) handoffs are
// cheap because everything is rank-32. Register-only gelu->MFMA16 middle loop.
// ---------------------------------------------------------------------------

typedef short bfrag8 __attribute__((ext_vector_type(8)));   // 8 bf16
typedef short bfrag4 __attribute__((ext_vector_type(4)));   // 4 bf16
typedef float f32x4  __attribute__((ext_vector_type(4)));

#define LMASK 8388607u      // 2^23 - 1
#define TWO_PI_OVER_L 7.4901405658478575e-7f

__device__ __forceinline__ unsigned short f2bf(float f) {
    unsigned u = __float_as_uint(f);
    u = (u + 0x7FFFu + ((u >> 16) & 1u)) >> 16;   // RTN-even
    return (unsigned short)u;
}
__device__ __forceinline__ unsigned pk2bf(float a, float b) {
    unsigned ua = __float_as_uint(a) + 0x8000u;
    unsigned ub = __float_as_uint(b) + 0x8000u;
    return __builtin_amdgcn_perm(ub, ua, 0x07060302u);
}
__device__ __forceinline__ float gelu_fast(float x) {
    float xx = x * x;
    float p  = fmaf(xx, 0.044715f, 1.0f);
    float t  = (x * p) * -2.3022083f;             // -2*sqrt(2/pi)*log2(e)
    float e  = __builtin_amdgcn_exp2f(t);
    return x * __builtin_amdgcn_rcpf(1.0f + e);
}

#if defined(__has_builtin)
#if __has_builtin(__builtin_amdgcn_mfma_f32_16x16x16bf16_1k)
#define HAVE_MFMA16_1K 1
#endif
#endif
__device__ __forceinline__ void mfma16(f32x4& acc, bfrag4 a, bfrag4 b) {
#ifdef HAVE_MFMA16_1K
    acc = __builtin_amdgcn_mfma_f32_16x16x16bf16_1k(a, b, acc, 0, 0, 0);
#else
    asm("v_mfma_f32_16x16x16_bf16 %0, %1, %2, %0" : "+v"(acc) : "v"(a), "v"(b));
#endif
}

// --------------------------- factor builder (verified r2-r4) ---------------
__device__ __forceinline__ void vt_body(const int* __restrict__ idx,
                                        unsigned short* __restrict__ out, int j) {
    unsigned m = ((unsigned)j) >> 1;
    int p = j & 1;
    #pragma unroll
    for (int k = 0; k < 16; ++k) {
        unsigned s  = ((unsigned)idx[k]) & LMASK;
        unsigned ph = (s * m) & LMASK;
        float sn, cs;
        __sincosf((float)ph * TWO_PI_OVER_L, &sn, &cs);
        float e0 = p ? sn : cs;
        float e1 = p ? cs : -sn;
        out[(size_t)j * 32 + 2 * k]     = f2bf(e0);
        out[(size_t)j * 32 + 2 * k + 1] = f2bf(e1);
    }
}

__global__ void k_build(const float* __restrict__ fcr, const float* __restrict__ fci,
                        const int* __restrict__ fidx, const float* __restrict__ fcs,
                        const float* __restrict__ prr, const float* __restrict__ pri,
                        const int* __restrict__ pidx, const float* __restrict__ prs,
                        unsigned short* __restrict__ ufct, unsigned short* __restrict__ vtfc,
                        unsigned short* __restrict__ u2t,  unsigned short* __restrict__ vprt) {
    int b = blockIdx.x, t = threadIdx.x;
    if (b < 8) {                       // U_fc^T [32 r][2048 i]
        int i = b * 256 + t;
        float sc = fcs[0] * (1.0f / 8388608.0f);
        #pragma unroll
        for (int k = 0; k < 16; ++k) {
            int v = fidx[k];
            bool keep = true;
            for (int j = k + 1; j < 16; ++j) keep = keep && (fidx[j] != v);
            unsigned s  = (((unsigned)v) << 12) & LMASK;
            unsigned ph = (s * (unsigned)i) & LMASK;
            float sn, cs;
            __sincosf((float)ph * TWO_PI_OVER_L, &sn, &cs);
            float a = keep ? fcr[k] * sc : 0.0f;
            float bb = keep ? fci[k] * sc : 0.0f;
            ufct[(size_t)(2 * k) * 2048 + i]     = f2bf(a * cs - bb * sn);
            ufct[(size_t)(2 * k + 1) * 2048 + i] = f2bf(a * sn + bb * cs);
        }
    } else if (b < 40) {               // V_fc^T [8192 f][32 r]
        vt_body(fidx, vtfc, (b - 8) * 256 + t);
    } else if (b < 72) {               // U_pr^T [32 r2][8192 f]
        int f = (b - 40) * 256 + t;
        float sc = prs[0] * (1.0f / 8388608.0f);
        #pragma unroll
        for (int k = 0; k < 16; ++k) {
            int v = pidx[k];
            bool keep = true;
            for (int j = k + 1; j < 16; ++j) keep = keep && (pidx[j] != v);
            unsigned s  = (((unsigned)v) << 10) & LMASK;
            unsigned ph = (s * (unsigned)f) & LMASK;
            float sn, cs;
            __sincosf((float)ph * TWO_PI_OVER_L, &sn, &cs);
            float a = keep ? prr[k] * sc : 0.0f;
            float bb = keep ? pri[k] * sc : 0.0f;
            u2t[(size_t)(2 * k) * 8192 + f]     = f2bf(a * cs - bb * sn);
            u2t[(size_t)(2 * k + 1) * 8192 + f] = f2bf(a * sn + bb * cs);
        }
    } else {                           // V_pr^T [2048 d][32 r2]
        vt_body(pidx, vprt, (b - 72) * 256 + t);
    }
}

// ------------------ kernel 1: T1 = x @ U_fc  (512 blocks) -------------------
__global__ __launch_bounds__(512, 4) void k_t1(
    const float* __restrict__ x,                 // [8192 tok][2048]
    const unsigned short* __restrict__ ufct,     // [32 r][2048 k]
    unsigned short* __restrict__ t1)             // [512 g][16 tok][32 r] bf16
{
    __shared__ float red[8 * 512];
    const int tid  = threadIdx.x;
    const int w    = tid >> 6;
    const int lane = tid & 63;
    const int lr   = lane & 15;
    const int hi   = lane >> 4;
    const size_t tok0 = (size_t)blockIdx.x * 16;

    f32x4 acc[2];
    { f32x4 z = {0.f,0.f,0.f,0.f}; acc[0] = z; acc[1] = z; }
    #pragma unroll 4
    for (int s = 0; s < 8; ++s) {
        int k = w * 256 + s * 32 + hi * 8;
        const float* xp = x + (tok0 + lr) * 2048 + k;
        float4 v0 = *(const float4*)xp;
        float4 v1 = *(const float4*)(xp + 4);
        uint4 aw = make_uint4(pk2bf(v0.x, v0.y), pk2bf(v0.z, v0.w),
                              pk2bf(v1.x, v1.y), pk2bf(v1.z, v1.w));
        bfrag8 af = __builtin_bit_cast(bfrag8, aw);
        bfrag8 b0 = *(const bfrag8*)(ufct + (size_t)lr * 2048 + k);
        bfrag8 b1 = *(const bfrag8*)(ufct + (size_t)(16 + lr) * 2048 + k);
        acc[0] = __builtin_amdgcn_mfma_f32_16x16x32_bf16(af, b0, acc[0], 0, 0, 0);
        acc[1] = __builtin_amdgcn_mfma_f32_16x16x32_bf16(af, b1, acc[1], 0, 0, 0);
    }
    #pragma unroll
    for (int nj = 0; nj < 2; ++nj)      // C: row=tok(4hi+r), col=r(nj*16+lr)
        #pragma unroll
        for (int r = 0; r < 4; ++r)
            red[w * 512 + (hi * 4 + r) * 32 + nj * 16 + lr] = acc[nj][r];
    __syncthreads();
    float s = 0.f;
    #pragma unroll
    for (int w2 = 0; w2 < 8; ++w2) s += red[w2 * 512 + tid];
    t1[(size_t)blockIdx.x * 512 + tid] = f2bf(s);
}

// -------- kernel 2: middle loop (1024 blocks = 512 g x 2 f-halves) ---------
// per wave: 16 iters x 32 f: S = Vfc*T1^T + b (MFMA32), gelu, T2 += (MFMA16)
__global__ __launch_bounds__(512, 4) void k_mid(
    const unsigned short* __restrict__ t1,       // [512 g][512]
    const unsigned short* __restrict__ vtfc,     // [8192 f][32 r]
    const unsigned short* __restrict__ u2t,      // [32 r2][8192 f]
    const float* __restrict__ fcb,               // [8192]
    float* __restrict__ t2p)                     // [2 fs][512 g][512] f32
{
    __shared__ float red[8 * 512];
    const int tid  = threadIdx.x;
    const int w    = tid >> 6;
    const int lane = tid & 63;
    const int lr   = lane & 15;
    const int hi   = lane >> 4;
    const int g    = blockIdx.y;
    const int fs   = blockIdx.x;

    // T1 as B-operand (col=tok=lr, k=r=8hi+j) — loop-invariant, from L2
    const bfrag8 t1b = *(const bfrag8*)(t1 + (size_t)g * 512 + lr * 32 + hi * 8);

    f32x4 a00, a01, a10, a11;           // [r2-tile][f-path] split accumulators
    { f32x4 z = {0.f,0.f,0.f,0.f}; a00 = z; a01 = z; a10 = z; a11 = z; }
    const unsigned short* u2b0 = u2t + (size_t)lr * 8192 + 4 * hi;        // r2 0..15
    const unsigned short* u2b1 = u2t + (size_t)(16 + lr) * 8192 + 4 * hi; // r2 16..31
    const int fbase = fs * 4096 + w * 512;

    #pragma unroll 2
    for (int it = 0; it < 16; ++it) {
        int fb = fbase + it * 32;
        bfrag8 va0 = *(const bfrag8*)(vtfc + (size_t)(fb + lr) * 32 + hi * 8);
        bfrag8 va1 = *(const bfrag8*)(vtfc + (size_t)(fb + 16 + lr) * 32 + hi * 8);
        float4 cb0 = *(const float4*)(fcb + fb + hi * 4);
        float4 cb1 = *(const float4*)(fcb + fb + 16 + hi * 4);
        bfrag4 u00 = *(const bfrag4*)(u2b0 + fb);
        bfrag4 u01 = *(const bfrag4*)(u2b0 + fb + 16);
        bfrag4 u10 = *(const bfrag4*)(u2b1 + fb);
        bfrag4 u11 = *(const bfrag4*)(u2b1 + fb + 16);
        // S^T tiles: C row = f(4hi+r), col = tok(lr); bias as C-operand
        f32x4 s0 = __builtin_amdgcn_mfma_f32_16x16x32_bf16(va0, t1b, __builtin_bit_cast(f32x4, cb0), 0, 0, 0);
        f32x4 s1 = __builtin_amdgcn_mfma_f32_16x16x32_bf16(va1, t1b, __builtin_bit_cast(f32x4, cb1), 0, 0, 0);
        // gelu + pack: C-layout == B-frag of K=16 MFMA (k=f, col=tok)
        uint2 hw0 = make_uint2(pk2bf(gelu_fast(s0[0]), gelu_fast(s0[1])),
                               pk2bf(gelu_fast(s0[2]), gelu_fast(s0[3])));
        uint2 hw1 = make_uint2(pk2bf(gelu_fast(s1[0]), gelu_fast(s1[1])),
                               pk2bf(gelu_fast(s1[2]), gelu_fast(s1[3])));
        bfrag4 h0 = __builtin_bit_cast(bfrag4, hw0);
        bfrag4 h1 = __builtin_bit_cast(bfrag4, hw1);
        // T2^T += U_pr^T * hT (independent chains per accumulator)
        mfma16(a00, u00, h0);
        mfma16(a10, u10, h0);
        mfma16(a01, u01, h1);
        mfma16(a11, u11, h1);
    }
    f32x4 t2v[2];
    t2v[0] = a00 + a01;                 // r2 0..15 tile
    t2v[1] = a10 + a11;                 // r2 16..31 tile

    // cross-wave reduce; transposed C-layout (r2 = rt*16+4hi+r, tok = lr)
    // rotation swizzle keeps banks <=4-way on write, conflict-free on read
    #pragma unroll
    for (int rt = 0; rt < 2; ++rt)
        #pragma unroll
        for (int r = 0; r < 4; ++r) {
            int r2 = rt * 16 + hi * 4 + r;
            red[w * 512 + lr * 32 + ((r2 + lr) & 31)] = t2v[rt][r];
        }
    __syncthreads();
    {
        int tok = tid >> 5, rr = tid & 31;
        int slot = tok * 32 + ((rr + tok) & 31);
        float s = 0.f;
        #pragma unroll
        for (int w2 = 0; w2 < 8; ++w2) s += red[w2 * 512 + slot];
        t2p[((size_t)fs * 512 + g) * 512 + tid] = s;   // [tok][r2], f32
    }
}

// ------ kernel 3: out = (T2p0+T2p1) @ V_pr^T + b2  (512 blocks) -------------
__global__ __launch_bounds__(512, 4) void k_out(
    const float* __restrict__ t2p,               // [2][512 g][512]
    const unsigned short* __restrict__ vprt,     // [2048 d][32 r2]
    const float* __restrict__ prb,               // [2048]
    float* __restrict__ out)                     // [8192 tok][2048]
{
    __shared__ unsigned short lT[512];
    const int tid  = threadIdx.x;
    const int w    = tid >> 6;
    const int lane = tid & 63;
    const int lr   = lane & 15;
    const int hi   = lane >> 4;
    const int g    = blockIdx.x;
    const size_t tok0 = (size_t)g * 16;

    {
        float s = t2p[(size_t)g * 512 + tid] + t2p[(size_t)(512 + g) * 512 + tid];
        lT[tid] = f2bf(s);
    }
    __syncthreads();
    const bfrag8 t2a = *(const bfrag8*)(lT + lr * 32 + hi * 8);
    #pragma unroll 4
    for (int nj = 0; nj < 16; ++nj) {
        int d = w * 256 + nj * 16 + lr;
        bfrag8 vp = *(const bfrag8*)(vprt + (size_t)d * 32 + hi * 8);
        float bn = prb[d];
        f32x4 c = {bn, bn, bn, bn};
        f32x4 o = __builtin_amdgcn_mfma_f32_16x16x32_bf16(t2a, vp, c, 0, 0, 0);
        #pragma unroll
        for (int r = 0; r < 4; ++r)
            out[(tok0 + hi * 4 + r) * 2048 + d] = o[r];
    }
}

// ---------------------------------------------------------------------------
extern "C" void kernel_launch(void* const* d_in, const int* in_sizes, int n_in,
                              void* d_out, int out_size, void* d_ws, size_t ws_size,
                              hipStream_t stream) {
    (void)in_sizes; (void)n_in; (void)out_size; (void)ws_size;
    const float* x   = (const float*)d_in[0];
    const float* fcr = (const float*)d_in[1];
    const float* fci = (const float*)d_in[2];
    const float* fcs = (const float*)d_in[3];
    const float* prr = (const float*)d_in[4];
    const float* pri = (const float*)d_in[5];
    const float* prs = (const float*)d_in[6];
    const float* fcb = (const float*)d_in[7];
    const float* prb = (const float*)d_in[8];
    const int* fidx  = (const int*)d_in[9];
    const int* pidx  = (const int*)d_in[10];
    float* out = (float*)d_out;
    char* ws = (char*)d_ws;

    size_t off = 0;
    auto take = [&](size_t bytes) { size_t p = off; off = (off + bytes + 255) & ~(size_t)255; return p; };
    unsigned short* ufct = (unsigned short*)(ws + take((size_t)32 * 2048 * 2));   // U_fc^T  [32][2048]
    unsigned short* vtfc = (unsigned short*)(ws + take((size_t)8192 * 32 * 2));   // V_fc^T  [8192][32]
    unsigned short* u2t  = (unsigned short*)(ws + take((size_t)32 * 8192 * 2));   // U_pr^T  [32][8192]
    unsigned short* vprt = (unsigned short*)(ws + take((size_t)2048 * 32 * 2));   // V_pr^T  [2048][32]
    unsigned short* t1   = (unsigned short*)(ws + take((size_t)8192 * 32 * 2));   // T1      [8192][32] bf16
    float*          t2p  = (float*)(ws + take((size_t)2 * 8192 * 32 * 4));        // T2 partials f32

    k_build<<<dim3(80), 256, 0, stream>>>(fcr, fci, fidx, fcs, prr, pri, pidx, prs,
                                          ufct, vtfc, u2t, vprt);
    k_t1 <<<dim3(512),      512, 0, stream>>>(x, ufct, t1);
    k_mid<<<dim3(2, 512),   512, 0, stream>>>(t1, vtfc, u2t, fcb, t2p);
    k_out<<<dim3(512),      512, 0, stream>>>(t2p, vprt, prb, out);
}

// Round 6
// 76.801 us; speedup vs baseline: 1.5909x; 1.5909x over previous
//
#include <hip/hip_runtime.h>
#include <stdint.h>

// ---------------------------------------------------------------------------
// FastHelgasonLayer: weights are IFFTs of 16-sparse spectra => exactly rank-32.
//   W_fc = U_fc(2048x32)V_fc(32x8192), W_proj = U_pr(8192x32)V_pr(32x2048)
// Round 6: k_mid loop-inverted — factor fragments wave-resident (loaded once),
// loop over token-groups with a single L1-resident t1 load per iteration.
// ---------------------------------------------------------------------------

typedef short bfrag8 __attribute__((ext_vector_type(8)));   // 8 bf16
typedef short bfrag4 __attribute__((ext_vector_type(4)));   // 4 bf16
typedef float f32x4  __attribute__((ext_vector_type(4)));

#define LMASK 8388607u      // 2^23 - 1
#define TWO_PI_OVER_L 7.4901405658478575e-7f

__device__ __forceinline__ unsigned short f2bf(float f) {
    unsigned u = __float_as_uint(f);
    u = (u + 0x7FFFu + ((u >> 16) & 1u)) >> 16;   // RTN-even
    return (unsigned short)u;
}
__device__ __forceinline__ unsigned pk2bf(float a, float b) {
    unsigned ua = __float_as_uint(a) + 0x8000u;
    unsigned ub = __float_as_uint(b) + 0x8000u;
    return __builtin_amdgcn_perm(ub, ua, 0x07060302u);
}
__device__ __forceinline__ float gelu_fast(float x) {
    float xx = x * x;
    float p  = fmaf(xx, 0.044715f, 1.0f);
    float t  = (x * p) * -2.3022083f;             // -2*sqrt(2/pi)*log2(e)
    float e  = __builtin_amdgcn_exp2f(t);
    return x * __builtin_amdgcn_rcpf(1.0f + e);
}

#if defined(__has_builtin)
#if __has_builtin(__builtin_amdgcn_mfma_f32_16x16x16bf16_1k)
#define HAVE_MFMA16_1K 1
#endif
#endif
__device__ __forceinline__ void mfma16(f32x4& acc, bfrag4 a, bfrag4 b) {
#ifdef HAVE_MFMA16_1K
    acc = __builtin_amdgcn_mfma_f32_16x16x16bf16_1k(a, b, acc, 0, 0, 0);
#else
    asm("v_mfma_f32_16x16x16_bf16 %0, %1, %2, %0" : "+v"(acc) : "v"(a), "v"(b));
#endif
}

// --------------------------- factor builder (verified r2-r5) ---------------
__device__ __forceinline__ void vt_body(const int* __restrict__ idx,
                                        unsigned short* __restrict__ out, int j) {
    unsigned m = ((unsigned)j) >> 1;
    int p = j & 1;
    #pragma unroll
    for (int k = 0; k < 16; ++k) {
        unsigned s  = ((unsigned)idx[k]) & LMASK;
        unsigned ph = (s * m) & LMASK;
        float sn, cs;
        __sincosf((float)ph * TWO_PI_OVER_L, &sn, &cs);
        float e0 = p ? sn : cs;
        float e1 = p ? cs : -sn;
        out[(size_t)j * 32 + 2 * k]     = f2bf(e0);
        out[(size_t)j * 32 + 2 * k + 1] = f2bf(e1);
    }
}

__global__ void k_build(const float* __restrict__ fcr, const float* __restrict__ fci,
                        const int* __restrict__ fidx, const float* __restrict__ fcs,
                        const float* __restrict__ prr, const float* __restrict__ pri,
                        const int* __restrict__ pidx, const float* __restrict__ prs,
                        unsigned short* __restrict__ ufct, unsigned short* __restrict__ vtfc,
                        unsigned short* __restrict__ u2t,  unsigned short* __restrict__ vprt) {
    int b = blockIdx.x, t = threadIdx.x;
    if (b < 8) {                       // U_fc^T [32 r][2048 i]
        int i = b * 256 + t;
        float sc = fcs[0] * (1.0f / 8388608.0f);
        #pragma unroll
        for (int k = 0; k < 16; ++k) {
            int v = fidx[k];
            bool keep = true;
            for (int j = k + 1; j < 16; ++j) keep = keep && (fidx[j] != v);
            unsigned s  = (((unsigned)v) << 12) & LMASK;
            unsigned ph = (s * (unsigned)i) & LMASK;
            float sn, cs;
            __sincosf((float)ph * TWO_PI_OVER_L, &sn, &cs);
            float a = keep ? fcr[k] * sc : 0.0f;
            float bb = keep ? fci[k] * sc : 0.0f;
            ufct[(size_t)(2 * k) * 2048 + i]     = f2bf(a * cs - bb * sn);
            ufct[(size_t)(2 * k + 1) * 2048 + i] = f2bf(a * sn + bb * cs);
        }
    } else if (b < 40) {               // V_fc^T [8192 f][32 r]
        vt_body(fidx, vtfc, (b - 8) * 256 + t);
    } else if (b < 72) {               // U_pr^T [32 r2][8192 f]
        int f = (b - 40) * 256 + t;
        float sc = prs[0] * (1.0f / 8388608.0f);
        #pragma unroll
        for (int k = 0; k < 16; ++k) {
            int v = pidx[k];
            bool keep = true;
            for (int j = k + 1; j < 16; ++j) keep = keep && (pidx[j] != v);
            unsigned s  = (((unsigned)v) << 10) & LMASK;
            unsigned ph = (s * (unsigned)f) & LMASK;
            float sn, cs;
            __sincosf((float)ph * TWO_PI_OVER_L, &sn, &cs);
            float a = keep ? prr[k] * sc : 0.0f;
            float bb = keep ? pri[k] * sc : 0.0f;
            u2t[(size_t)(2 * k) * 8192 + f]     = f2bf(a * cs - bb * sn);
            u2t[(size_t)(2 * k + 1) * 8192 + f] = f2bf(a * sn + bb * cs);
        }
    } else {                           // V_pr^T [2048 d][32 r2]
        vt_body(pidx, vprt, (b - 72) * 256 + t);
    }
}

// ------------------ kernel 1: T1 = x @ U_fc  (512 blocks) -------------------
__global__ __launch_bounds__(512, 4) void k_t1(
    const float* __restrict__ x,                 // [8192 tok][2048]
    const unsigned short* __restrict__ ufct,     // [32 r][2048 k]
    unsigned short* __restrict__ t1)             // [512 g][16 tok][32 r] bf16
{
    __shared__ float red[8 * 512];
    const int tid  = threadIdx.x;
    const int w    = tid >> 6;
    const int lane = tid & 63;
    const int lr   = lane & 15;
    const int hi   = lane >> 4;
    const size_t tok0 = (size_t)blockIdx.x * 16;

    f32x4 acc[2];
    { f32x4 z = {0.f,0.f,0.f,0.f}; acc[0] = z; acc[1] = z; }
    #pragma unroll 4
    for (int s = 0; s < 8; ++s) {
        int k = w * 256 + s * 32 + hi * 8;
        const float* xp = x + (tok0 + lr) * 2048 + k;
        float4 v0 = *(const float4*)xp;
        float4 v1 = *(const float4*)(xp + 4);
        uint4 aw = make_uint4(pk2bf(v0.x, v0.y), pk2bf(v0.z, v0.w),
                              pk2bf(v1.x, v1.y), pk2bf(v1.z, v1.w));
        bfrag8 af = __builtin_bit_cast(bfrag8, aw);
        bfrag8 b0 = *(const bfrag8*)(ufct + (size_t)lr * 2048 + k);
        bfrag8 b1 = *(const bfrag8*)(ufct + (size_t)(16 + lr) * 2048 + k);
        acc[0] = __builtin_amdgcn_mfma_f32_16x16x32_bf16(af, b0, acc[0], 0, 0, 0);
        acc[1] = __builtin_amdgcn_mfma_f32_16x16x32_bf16(af, b1, acc[1], 0, 0, 0);
    }
    #pragma unroll
    for (int nj = 0; nj < 2; ++nj)      // C: row=tok(4hi+r), col=r(nj*16+lr)
        #pragma unroll
        for (int r = 0; r < 4; ++r)
            red[w * 512 + (hi * 4 + r) * 32 + nj * 16 + lr] = acc[nj][r];
    __syncthreads();
    float s = 0.f;
    #pragma unroll
    for (int w2 = 0; w2 < 8; ++w2) s += red[w2 * 512 + tid];
    t1[(size_t)blockIdx.x * 512 + tid] = f2bf(s);
}

// -------- kernel 2: middle loop, loop-inverted (16 fc x 32 gtiles) ----------
// wave holds factor frags for 64 f in registers; iterates 16 token-groups.
__global__ __launch_bounds__(512, 4) void k_mid(
    const unsigned short* __restrict__ t1,       // [512 g][512]
    const unsigned short* __restrict__ vtfc,     // [8192 f][32 r]
    const unsigned short* __restrict__ u2t,      // [32 r2][8192 f]
    const float* __restrict__ fcb,               // [8192]
    float* __restrict__ t2p)                     // [16 fc][512 g][512] f32
{
    __shared__ float red[8 * 512];
    const int tid  = threadIdx.x;
    const int w    = tid >> 6;
    const int lane = tid & 63;
    const int lr   = lane & 15;
    const int hi   = lane >> 4;
    const int fc   = blockIdx.x;            // f-chunk 0..15 (512 f each)
    const int g0   = blockIdx.y * 16;       // token-group base

    // ---- load factor fragments once: 2 f-slices of 32 f per wave ----------
    bfrag8 va0[2], va1[2];
    bfrag4 u00[2], u01[2], u10[2], u11[2];
    f32x4  cb0[2], cb1[2];
    #pragma unroll
    for (int sl = 0; sl < 2; ++sl) {
        int fb = fc * 512 + w * 64 + sl * 32;
        va0[sl] = *(const bfrag8*)(vtfc + (size_t)(fb + lr) * 32 + hi * 8);
        va1[sl] = *(const bfrag8*)(vtfc + (size_t)(fb + 16 + lr) * 32 + hi * 8);
        cb0[sl] = *(const f32x4*)(fcb + fb + hi * 4);
        cb1[sl] = *(const f32x4*)(fcb + fb + 16 + hi * 4);
        u00[sl] = *(const bfrag4*)(u2t + (size_t)lr * 8192 + fb + 4 * hi);
        u01[sl] = *(const bfrag4*)(u2t + (size_t)lr * 8192 + fb + 16 + 4 * hi);
        u10[sl] = *(const bfrag4*)(u2t + (size_t)(16 + lr) * 8192 + fb + 4 * hi);
        u11[sl] = *(const bfrag4*)(u2t + (size_t)(16 + lr) * 8192 + fb + 16 + 4 * hi);
    }

    // T1 B-fragment for first g; prefetch pattern: next-g load issued early
    bfrag8 t1b = *(const bfrag8*)(t1 + (size_t)g0 * 512 + lr * 32 + hi * 8);

    #pragma unroll 1
    for (int gi = 0; gi < 16; ++gi) {
        bfrag8 cur = t1b;
        {   // issue next iteration's t1 load early (hidden under gelu+reduce)
            int gn = g0 + ((gi + 1) & 15);
            t1b = *(const bfrag8*)(t1 + (size_t)gn * 512 + lr * 32 + hi * 8);
        }
        f32x4 t2a0 = {0.f,0.f,0.f,0.f}, t2a1 = {0.f,0.f,0.f,0.f};
        #pragma unroll
        for (int sl = 0; sl < 2; ++sl) {
            // S^T = Vfc(16f x 32r) @ T1^T(32r x 16tok) + bias(C-op); row=f, col=tok
            f32x4 s0 = __builtin_amdgcn_mfma_f32_16x16x32_bf16(va0[sl], cur, cb0[sl], 0, 0, 0);
            f32x4 s1 = __builtin_amdgcn_mfma_f32_16x16x32_bf16(va1[sl], cur, cb1[sl], 0, 0, 0);
            // gelu + pack: C-layout == B-frag of K=16 MFMA (k=f, col=tok)
            uint2 hw0 = make_uint2(pk2bf(gelu_fast(s0[0]), gelu_fast(s0[1])),
                                   pk2bf(gelu_fast(s0[2]), gelu_fast(s0[3])));
            uint2 hw1 = make_uint2(pk2bf(gelu_fast(s1[0]), gelu_fast(s1[1])),
                                   pk2bf(gelu_fast(s1[2]), gelu_fast(s1[3])));
            bfrag4 h0 = __builtin_bit_cast(bfrag4, hw0);
            bfrag4 h1 = __builtin_bit_cast(bfrag4, hw1);
            // T2^T += U_pr^T(16r2 x 16f) * hT(16f x 16tok); both slices same acc
            mfma16(t2a0, u00[sl], h0);
            mfma16(t2a1, u10[sl], h0);
            mfma16(t2a0, u01[sl], h1);
            mfma16(t2a1, u11[sl], h1);
        }
        // ---- cross-wave reduce (rotation swizzle, verified r5) -------------
        #pragma unroll
        for (int rt = 0; rt < 2; ++rt) {
            f32x4 v = rt ? t2a1 : t2a0;
            #pragma unroll
            for (int r = 0; r < 4; ++r) {
                int r2 = rt * 16 + hi * 4 + r;     // (r2, tok=lr)
                red[w * 512 + lr * 32 + ((r2 + lr) & 31)] = v[r];
            }
        }
        __syncthreads();
        {
            int tok = tid >> 5, rr = tid & 31;
            int slot = tok * 32 + ((rr + tok) & 31);
            float s = 0.f;
            #pragma unroll
            for (int w2 = 0; w2 < 8; ++w2) s += red[w2 * 512 + slot];
            t2p[((size_t)fc * 512 + (g0 + gi)) * 512 + tid] = s;   // [tok][r2]
        }
        __syncthreads();
    }
}

// ------ kernel 3: out = (sum_fc T2p) @ V_pr^T + b2  (512 blocks) ------------
__global__ __launch_bounds__(512, 4) void k_out(
    const float* __restrict__ t2p,               // [16][512 g][512]
    const unsigned short* __restrict__ vprt,     // [2048 d][32 r2]
    const float* __restrict__ prb,               // [2048]
    float* __restrict__ out)                     // [8192 tok][2048]
{
    __shared__ unsigned short lT[512];
    const int tid  = threadIdx.x;
    const int w    = tid >> 6;
    const int lane = tid & 63;
    const int lr   = lane & 15;
    const int hi   = lane >> 4;
    const int g    = blockIdx.x;
    const size_t tok0 = (size_t)g * 16;

    {
        float s = 0.f;
        #pragma unroll
        for (int c = 0; c < 16; ++c)
            s += t2p[((size_t)c * 512 + g) * 512 + tid];
        lT[tid] = f2bf(s);
    }
    __syncthreads();
    const bfrag8 t2a = *(const bfrag8*)(lT + lr * 32 + hi * 8);
    #pragma unroll 4
    for (int nj = 0; nj < 16; ++nj) {
        int d = w * 256 + nj * 16 + lr;
        bfrag8 vp = *(const bfrag8*)(vprt + (size_t)d * 32 + hi * 8);
        float bn = prb[d];
        f32x4 c = {bn, bn, bn, bn};
        f32x4 o = __builtin_amdgcn_mfma_f32_16x16x32_bf16(t2a, vp, c, 0, 0, 0);
        #pragma unroll
        for (int r = 0; r < 4; ++r)
            out[(tok0 + hi * 4 + r) * 2048 + d] = o[r];
    }
}

// ---------------------------------------------------------------------------
extern "C" void kernel_launch(void* const* d_in, const int* in_sizes, int n_in,
                              void* d_out, int out_size, void* d_ws, size_t ws_size,
                              hipStream_t stream) {
    (void)in_sizes; (void)n_in; (void)out_size; (void)ws_size;
    const float* x   = (const float*)d_in[0];
    const float* fcr = (const float*)d_in[1];
    const float* fci = (const float*)d_in[2];
    const float* fcs = (const float*)d_in[3];
    const float* prr = (const float*)d_in[4];
    const float* pri = (const float*)d_in[5];
    const float* prs = (const float*)d_in[6];
    const float* fcb = (const float*)d_in[7];
    const float* prb = (const float*)d_in[8];
    const int* fidx  = (const int*)d_in[9];
    const int* pidx  = (const int*)d_in[10];
    float* out = (float*)d_out;
    char* ws = (char*)d_ws;

    size_t off = 0;
    auto take = [&](size_t bytes) { size_t p = off; off = (off + bytes + 255) & ~(size_t)255; return p; };
    unsigned short* ufct = (unsigned short*)(ws + take((size_t)32 * 2048 * 2));   // U_fc^T  [32][2048]
    unsigned short* vtfc = (unsigned short*)(ws + take((size_t)8192 * 32 * 2));   // V_fc^T  [8192][32]
    unsigned short* u2t  = (unsigned short*)(ws + take((size_t)32 * 8192 * 2));   // U_pr^T  [32][8192]
    unsigned short* vprt = (unsigned short*)(ws + take((size_t)2048 * 32 * 2));   // V_pr^T  [2048][32]
    unsigned short* t1   = (unsigned short*)(ws + take((size_t)8192 * 32 * 2));   // T1      [8192][32] bf16
    float*          t2p  = (float*)(ws + take((size_t)16 * 8192 * 32 * 4));       // T2 partials [16][8192][32]

    k_build<<<dim3(80), 256, 0, stream>>>(fcr, fci, fidx, fcs, prr, pri, pidx, prs,
                                          ufct, vtfc, u2t, vprt);
    k_t1 <<<dim3(512),    512, 0, stream>>>(x, ufct, t1);
    k_mid<<<dim3(16, 32), 512, 0, stream>>>(t1, vtfc, u2t, fcb, t2p);
    k_out<<<dim3(512),    512, 0, stream>>>(t2p, vprt, prb, out);
}

// Round 7
// 74.518 us; speedup vs baseline: 1.6396x; 1.0306x over previous
//
#include <hip/hip_runtime.h>
#include <stdint.h>

// ---------------------------------------------------------------------------
// FastHelgasonLayer: weights are IFFTs of 16-sparse spectra => exactly rank-32.
//   W_fc = U_fc(2048x32)V_fc(32x8192), W_proj = U_pr(8192x32)V_pr(32x2048)
// Round 7: k_mid processes 2 token-groups per reduce round (2x ILP, half the
// barriers); t2p partials in bf16 (halves partial HBM traffic).
// ---------------------------------------------------------------------------

typedef short bfrag8 __attribute__((ext_vector_type(8)));   // 8 bf16
typedef short bfrag4 __attribute__((ext_vector_type(4)));   // 4 bf16
typedef float f32x4  __attribute__((ext_vector_type(4)));

#define LMASK 8388607u      // 2^23 - 1
#define TWO_PI_OVER_L 7.4901405658478575e-7f

__device__ __forceinline__ unsigned short f2bf(float f) {
    unsigned u = __float_as_uint(f);
    u = (u + 0x7FFFu + ((u >> 16) & 1u)) >> 16;   // RTN-even
    return (unsigned short)u;
}
__device__ __forceinline__ float bf2f(unsigned short h) {
    unsigned u = ((unsigned)h) << 16;
    return __builtin_bit_cast(float, u);
}
__device__ __forceinline__ unsigned pk2bf(float a, float b) {
    unsigned ua = __float_as_uint(a) + 0x8000u;
    unsigned ub = __float_as_uint(b) + 0x8000u;
    return __builtin_amdgcn_perm(ub, ua, 0x07060302u);
}
__device__ __forceinline__ float gelu_fast(float x) {
    float xx = x * x;
    float p  = fmaf(xx, 0.044715f, 1.0f);
    float t  = (x * p) * -2.3022083f;             // -2*sqrt(2/pi)*log2(e)
    float e  = __builtin_amdgcn_exp2f(t);
    return x * __builtin_amdgcn_rcpf(1.0f + e);
}

#if defined(__has_builtin)
#if __has_builtin(__builtin_amdgcn_mfma_f32_16x16x16bf16_1k)
#define HAVE_MFMA16_1K 1
#endif
#endif
__device__ __forceinline__ void mfma16(f32x4& acc, bfrag4 a, bfrag4 b) {
#ifdef HAVE_MFMA16_1K
    acc = __builtin_amdgcn_mfma_f32_16x16x16bf16_1k(a, b, acc, 0, 0, 0);
#else
    asm("v_mfma_f32_16x16x16_bf16 %0, %1, %2, %0" : "+v"(acc) : "v"(a), "v"(b));
#endif
}

// --------------------------- factor builder (verified r2-r6) ---------------
__device__ __forceinline__ void vt_body(const int* __restrict__ idx,
                                        unsigned short* __restrict__ out, int j) {
    unsigned m = ((unsigned)j) >> 1;
    int p = j & 1;
    #pragma unroll
    for (int k = 0; k < 16; ++k) {
        unsigned s  = ((unsigned)idx[k]) & LMASK;
        unsigned ph = (s * m) & LMASK;
        float sn, cs;
        __sincosf((float)ph * TWO_PI_OVER_L, &sn, &cs);
        float e0 = p ? sn : cs;
        float e1 = p ? cs : -sn;
        out[(size_t)j * 32 + 2 * k]     = f2bf(e0);
        out[(size_t)j * 32 + 2 * k + 1] = f2bf(e1);
    }
}

__global__ void k_build(const float* __restrict__ fcr, const float* __restrict__ fci,
                        const int* __restrict__ fidx, const float* __restrict__ fcs,
                        const float* __restrict__ prr, const float* __restrict__ pri,
                        const int* __restrict__ pidx, const float* __restrict__ prs,
                        unsigned short* __restrict__ ufct, unsigned short* __restrict__ vtfc,
                        unsigned short* __restrict__ u2t,  unsigned short* __restrict__ vprt) {
    int b = blockIdx.x, t = threadIdx.x;
    if (b < 8) {                       // U_fc^T [32 r][2048 i]
        int i = b * 256 + t;
        float sc = fcs[0] * (1.0f / 8388608.0f);
        #pragma unroll
        for (int k = 0; k < 16; ++k) {
            int v = fidx[k];
            bool keep = true;
            for (int j = k + 1; j < 16; ++j) keep = keep && (fidx[j] != v);
            unsigned s  = (((unsigned)v) << 12) & LMASK;
            unsigned ph = (s * (unsigned)i) & LMASK;
            float sn, cs;
            __sincosf((float)ph * TWO_PI_OVER_L, &sn, &cs);
            float a = keep ? fcr[k] * sc : 0.0f;
            float bb = keep ? fci[k] * sc : 0.0f;
            ufct[(size_t)(2 * k) * 2048 + i]     = f2bf(a * cs - bb * sn);
            ufct[(size_t)(2 * k + 1) * 2048 + i] = f2bf(a * sn + bb * cs);
        }
    } else if (b < 40) {               // V_fc^T [8192 f][32 r]
        vt_body(fidx, vtfc, (b - 8) * 256 + t);
    } else if (b < 72) {               // U_pr^T [32 r2][8192 f]
        int f = (b - 40) * 256 + t;
        float sc = prs[0] * (1.0f / 8388608.0f);
        #pragma unroll
        for (int k = 0; k < 16; ++k) {
            int v = pidx[k];
            bool keep = true;
            for (int j = k + 1; j < 16; ++j) keep = keep && (pidx[j] != v);
            unsigned s  = (((unsigned)v) << 10) & LMASK;
            unsigned ph = (s * (unsigned)f) & LMASK;
            float sn, cs;
            __sincosf((float)ph * TWO_PI_OVER_L, &sn, &cs);
            float a = keep ? prr[k] * sc : 0.0f;
            float bb = keep ? pri[k] * sc : 0.0f;
            u2t[(size_t)(2 * k) * 8192 + f]     = f2bf(a * cs - bb * sn);
            u2t[(size_t)(2 * k + 1) * 8192 + f] = f2bf(a * sn + bb * cs);
        }
    } else {                           // V_pr^T [2048 d][32 r2]
        vt_body(pidx, vprt, (b - 72) * 256 + t);
    }
}

// ------------------ kernel 1: T1 = x @ U_fc  (512 blocks) -------------------
__global__ __launch_bounds__(512, 4) void k_t1(
    const float* __restrict__ x,                 // [8192 tok][2048]
    const unsigned short* __restrict__ ufct,     // [32 r][2048 k]
    unsigned short* __restrict__ t1)             // [512 g][16 tok][32 r] bf16
{
    __shared__ float red[8 * 512];
    const int tid  = threadIdx.x;
    const int w    = tid >> 6;
    const int lane = tid & 63;
    const int lr   = lane & 15;
    const int hi   = lane >> 4;
    const size_t tok0 = (size_t)blockIdx.x * 16;

    f32x4 acc[2];
    { f32x4 z = {0.f,0.f,0.f,0.f}; acc[0] = z; acc[1] = z; }
    #pragma unroll 4
    for (int s = 0; s < 8; ++s) {
        int k = w * 256 + s * 32 + hi * 8;
        const float* xp = x + (tok0 + lr) * 2048 + k;
        float4 v0 = *(const float4*)xp;
        float4 v1 = *(const float4*)(xp + 4);
        uint4 aw = make_uint4(pk2bf(v0.x, v0.y), pk2bf(v0.z, v0.w),
                              pk2bf(v1.x, v1.y), pk2bf(v1.z, v1.w));
        bfrag8 af = __builtin_bit_cast(bfrag8, aw);
        bfrag8 b0 = *(const bfrag8*)(ufct + (size_t)lr * 2048 + k);
        bfrag8 b1 = *(const bfrag8*)(ufct + (size_t)(16 + lr) * 2048 + k);
        acc[0] = __builtin_amdgcn_mfma_f32_16x16x32_bf16(af, b0, acc[0], 0, 0, 0);
        acc[1] = __builtin_amdgcn_mfma_f32_16x16x32_bf16(af, b1, acc[1], 0, 0, 0);
    }
    #pragma unroll
    for (int nj = 0; nj < 2; ++nj)      // C: row=tok(4hi+r), col=r(nj*16+lr)
        #pragma unroll
        for (int r = 0; r < 4; ++r)
            red[w * 512 + (hi * 4 + r) * 32 + nj * 16 + lr] = acc[nj][r];
    __syncthreads();
    float s = 0.f;
    #pragma unroll
    for (int w2 = 0; w2 < 8; ++w2) s += red[w2 * 512 + tid];
    t1[(size_t)blockIdx.x * 512 + tid] = f2bf(s);
}

// -------- kernel 2: middle loop (16 fc x 32 gtiles), 2 g per round ---------
// wave holds factor frags for 64 f in registers; 8 pair-rounds x 2 groups.
__global__ __launch_bounds__(512, 4) void k_mid(
    const unsigned short* __restrict__ t1,       // [512 g][512]
    const unsigned short* __restrict__ vtfc,     // [8192 f][32 r]
    const unsigned short* __restrict__ u2t,      // [32 r2][8192 f]
    const float* __restrict__ fcb,               // [8192]
    unsigned short* __restrict__ t2p)            // [16 fc][512 g][512] bf16
{
    __shared__ float red[2 * 8 * 512];           // [pair][wave][512] = 32 KB
    const int tid  = threadIdx.x;
    const int w    = tid >> 6;
    const int lane = tid & 63;
    const int lr   = lane & 15;
    const int hi   = lane >> 4;
    const int fc   = blockIdx.x;            // f-chunk 0..15 (512 f each)
    const int g0   = blockIdx.y * 16;       // token-group base (16 groups)

    // ---- load factor fragments once: 2 f-slices of 32 f per wave ----------
    bfrag8 va0[2], va1[2];
    bfrag4 u00[2], u01[2], u10[2], u11[2];
    f32x4  cb0[2], cb1[2];
    #pragma unroll
    for (int sl = 0; sl < 2; ++sl) {
        int fb = fc * 512 + w * 64 + sl * 32;
        va0[sl] = *(const bfrag8*)(vtfc + (size_t)(fb + lr) * 32 + hi * 8);
        va1[sl] = *(const bfrag8*)(vtfc + (size_t)(fb + 16 + lr) * 32 + hi * 8);
        cb0[sl] = *(const f32x4*)(fcb + fb + hi * 4);
        cb1[sl] = *(const f32x4*)(fcb + fb + 16 + hi * 4);
        u00[sl] = *(const bfrag4*)(u2t + (size_t)lr * 8192 + fb + 4 * hi);
        u01[sl] = *(const bfrag4*)(u2t + (size_t)lr * 8192 + fb + 16 + 4 * hi);
        u10[sl] = *(const bfrag4*)(u2t + (size_t)(16 + lr) * 8192 + fb + 4 * hi);
        u11[sl] = *(const bfrag4*)(u2t + (size_t)(16 + lr) * 8192 + fb + 16 + 4 * hi);
    }
    const int toff = lr * 32 + hi * 8;

    #pragma unroll 1
    for (int pi = 0; pi < 8; ++pi) {
        int ga = g0 + pi * 2, gb = ga + 1;
        bfrag8 tA = *(const bfrag8*)(t1 + (size_t)ga * 512 + toff);
        bfrag8 tB = *(const bfrag8*)(t1 + (size_t)gb * 512 + toff);
        f32x4 aA0 = {0.f,0.f,0.f,0.f}, aA1 = {0.f,0.f,0.f,0.f};
        f32x4 aB0 = {0.f,0.f,0.f,0.f}, aB1 = {0.f,0.f,0.f,0.f};
        #pragma unroll
        for (int sl = 0; sl < 2; ++sl) {
            // two independent chains (group A, group B) interleave for ILP
            f32x4 sA0 = __builtin_amdgcn_mfma_f32_16x16x32_bf16(va0[sl], tA, cb0[sl], 0, 0, 0);
            f32x4 sB0 = __builtin_amdgcn_mfma_f32_16x16x32_bf16(va0[sl], tB, cb0[sl], 0, 0, 0);
            f32x4 sA1 = __builtin_amdgcn_mfma_f32_16x16x32_bf16(va1[sl], tA, cb1[sl], 0, 0, 0);
            f32x4 sB1 = __builtin_amdgcn_mfma_f32_16x16x32_bf16(va1[sl], tB, cb1[sl], 0, 0, 0);
            uint2 hA0 = make_uint2(pk2bf(gelu_fast(sA0[0]), gelu_fast(sA0[1])),
                                   pk2bf(gelu_fast(sA0[2]), gelu_fast(sA0[3])));
            uint2 hB0 = make_uint2(pk2bf(gelu_fast(sB0[0]), gelu_fast(sB0[1])),
                                   pk2bf(gelu_fast(sB0[2]), gelu_fast(sB0[3])));
            uint2 hA1 = make_uint2(pk2bf(gelu_fast(sA1[0]), gelu_fast(sA1[1])),
                                   pk2bf(gelu_fast(sA1[2]), gelu_fast(sA1[3])));
            uint2 hB1 = make_uint2(pk2bf(gelu_fast(sB1[0]), gelu_fast(sB1[1])),
                                   pk2bf(gelu_fast(sB1[2]), gelu_fast(sB1[3])));
            bfrag4 fA0 = __builtin_bit_cast(bfrag4, hA0);
            bfrag4 fB0 = __builtin_bit_cast(bfrag4, hB0);
            bfrag4 fA1 = __builtin_bit_cast(bfrag4, hA1);
            bfrag4 fB1 = __builtin_bit_cast(bfrag4, hB1);
            mfma16(aA0, u00[sl], fA0);
            mfma16(aB0, u00[sl], fB0);
            mfma16(aA1, u10[sl], fA0);
            mfma16(aB1, u10[sl], fB0);
            mfma16(aA0, u01[sl], fA1);
            mfma16(aB0, u01[sl], fB1);
            mfma16(aA1, u11[sl], fA1);
            mfma16(aB1, u11[sl], fB1);
        }
        // ---- cross-wave reduce for both groups (rotation swizzle, r5/r6) ---
        #pragma unroll
        for (int r = 0; r < 4; ++r) {
            int r2a = hi * 4 + r, r2b = 16 + hi * 4 + r;
            red[(0 * 8 + w) * 512 + lr * 32 + ((r2a + lr) & 31)] = aA0[r];
            red[(0 * 8 + w) * 512 + lr * 32 + ((r2b + lr) & 31)] = aA1[r];
            red[(1 * 8 + w) * 512 + lr * 32 + ((r2a + lr) & 31)] = aB0[r];
            red[(1 * 8 + w) * 512 + lr * 32 + ((r2b + lr) & 31)] = aB1[r];
        }
        __syncthreads();
        {
            int tok = tid >> 5, rr = tid & 31;
            int slot = tok * 32 + ((rr + tok) & 31);
            float sa = 0.f, sb = 0.f;
            #pragma unroll
            for (int w2 = 0; w2 < 8; ++w2) {
                sa += red[(0 * 8 + w2) * 512 + slot];
                sb += red[(1 * 8 + w2) * 512 + slot];
            }
            t2p[((size_t)fc * 512 + ga) * 512 + tid] = f2bf(sa);   // [tok][r2]
            t2p[((size_t)fc * 512 + gb) * 512 + tid] = f2bf(sb);
        }
        __syncthreads();
    }
}

// ------ kernel 3: out = (sum_fc T2p) @ V_pr^T + b2  (512 blocks) ------------
__global__ __launch_bounds__(512, 4) void k_out(
    const unsigned short* __restrict__ t2p,      // [16][512 g][512] bf16
    const unsigned short* __restrict__ vprt,     // [2048 d][32 r2]
    const float* __restrict__ prb,               // [2048]
    float* __restrict__ out)                     // [8192 tok][2048]
{
    __shared__ unsigned short lT[512];
    const int tid  = threadIdx.x;
    const int w    = tid >> 6;
    const int lane = tid & 63;
    const int lr   = lane & 15;
    const int hi   = lane >> 4;
    const int g    = blockIdx.x;
    const size_t tok0 = (size_t)g * 16;

    {
        float s = 0.f;
        #pragma unroll
        for (int c = 0; c < 16; ++c)
            s += bf2f(t2p[((size_t)c * 512 + g) * 512 + tid]);
        lT[tid] = f2bf(s);
    }
    __syncthreads();
    const bfrag8 t2a = *(const bfrag8*)(lT + lr * 32 + hi * 8);
    #pragma unroll 4
    for (int nj = 0; nj < 16; ++nj) {
        int d = w * 256 + nj * 16 + lr;
        bfrag8 vp = *(const bfrag8*)(vprt + (size_t)d * 32 + hi * 8);
        float bn = prb[d];
        f32x4 c = {bn, bn, bn, bn};
        f32x4 o = __builtin_amdgcn_mfma_f32_16x16x32_bf16(t2a, vp, c, 0, 0, 0);
        #pragma unroll
        for (int r = 0; r < 4; ++r)
            out[(tok0 + hi * 4 + r) * 2048 + d] = o[r];
    }
}

// ---------------------------------------------------------------------------
extern "C" void kernel_launch(void* const* d_in, const int* in_sizes, int n_in,
                              void* d_out, int out_size, void* d_ws, size_t ws_size,
                              hipStream_t stream) {
    (void)in_sizes; (void)n_in; (void)out_size; (void)ws_size;
    const float* x   = (const float*)d_in[0];
    const float* fcr = (const float*)d_in[1];
    const float* fci = (const float*)d_in[2];
    const float* fcs = (const float*)d_in[3];
    const float* prr = (const float*)d_in[4];
    const float* pri = (const float*)d_in[5];
    const float* prs = (const float*)d_in[6];
    const float* fcb = (const float*)d_in[7];
    const float* prb = (const float*)d_in[8];
    const int* fidx  = (const int*)d_in[9];
    const int* pidx  = (const int*)d_in[10];
    float* out = (float*)d_out;
    char* ws = (char*)d_ws;

    size_t off = 0;
    auto take = [&](size_t bytes) { size_t p = off; off = (off + bytes + 255) & ~(size_t)255; return p; };
    unsigned short* ufct = (unsigned short*)(ws + take((size_t)32 * 2048 * 2));   // U_fc^T  [32][2048]
    unsigned short* vtfc = (unsigned short*)(ws + take((size_t)8192 * 32 * 2));   // V_fc^T  [8192][32]
    unsigned short* u2t  = (unsigned short*)(ws + take((size_t)32 * 8192 * 2));   // U_pr^T  [32][8192]
    unsigned short* vprt = (unsigned short*)(ws + take((size_t)2048 * 32 * 2));   // V_pr^T  [2048][32]
    unsigned short* t1   = (unsigned short*)(ws + take((size_t)8192 * 32 * 2));   // T1      [8192][32] bf16
    unsigned short* t2p  = (unsigned short*)(ws + take((size_t)16 * 8192 * 32 * 2)); // T2 partials bf16

    k_build<<<dim3(80), 256, 0, stream>>>(fcr, fci, fidx, fcs, prr, pri, pidx, prs,
                                          ufct, vtfc, u2t, vprt);
    k_t1 <<<dim3(512),    512, 0, stream>>>(x, ufct, t1);
    k_mid<<<dim3(16, 32), 512, 0, stream>>>(t1, vtfc, u2t, fcb, t2p);
    k_out<<<dim3(512),    512, 0, stream>>>(t2p, vprt, prb, out);
}